// Round 15
// baseline (148.104 us; speedup 1.0000x reference)
//
#include <hip/hip_runtime.h>
#include <stdint.h>

// Chamfer L1, B=4, N=M=8192, 3-D points — SYMMETRIC single-pass, FUSED,
// 2 dispatches (init + sym). Each pairwise distance computed ONCE,
// updating both forward (pred) row-min and backward (target) col-min.
// u16 fixed-point quantization (4096/unit, +8 offset) inlined in prologue.
//   pair = 2x v_sad_u16 (4 cyc) + v_min3_u32 folding => ~10.75 cyc/pair
//   for BOTH directions. Ring floor ~18.3 us.
// Wave tile = 128 preds x 256 targets; 4 groups of 16 lanes; lane owns
// 8 preds (stationary rows) + 4 targets (rotating cols via in-place DPP
// row_ror:1, zero LDS). 8192 waves = 2048 blocks, 8 waves/SIMD.
// R11/R13 spill pathology (VGPR=28, state demoted to scratch when the
// function grew): fixed by NAMED SCALARS ONLY — no indexable arrays exist
// in the hot kernel, so scratch demotion is impossible (rule #20).

#define BATCH    4
#define NPTS     8192
#define QSCALE   4096.0f
#define QOFFS    8.0f
#define NBLK     2048

static __device__ __forceinline__ uint32_t sad_u16(uint32_t a, uint32_t b, uint32_t c) {
#if __has_builtin(__builtin_amdgcn_sad_u16)
    return __builtin_amdgcn_sad_u16(a, b, c);
#else
    uint32_t d;
    asm("v_sad_u16 %0, %1, %2, %3" : "=v"(d) : "v"(a), "v"(b), "v"(c));
    return d;
#endif
}

static __device__ __forceinline__ uint32_t min3_u32(uint32_t a, uint32_t b, uint32_t c) {
    uint32_t d;
    asm("v_min3_u32 %0, %1, %2, %3" : "=v"(d) : "v"(a), "v"(b), "v"(c));
    return d;
}

static __device__ __forceinline__ uint32_t umin32(uint32_t a, uint32_t b) {
    return a < b ? a : b;
}

// in-place rotate within each 16-lane row: lane l receives lane (l+1)&15
static __device__ __forceinline__ uint32_t rot16(uint32_t v) {
    return (uint32_t)__builtin_amdgcn_update_dpp((int)v, (int)v, 0x121, 0xF, 0xF, false);
}

static __device__ __forceinline__ uint32_t quant(float x) {
    float v = (x + QOFFS) * QSCALE;
    v = fminf(fmaxf(v, 0.0f), 65535.0f);
    return (uint32_t)(v + 0.5f);
}

// ws layout: [0, 256K): wsmin (64K u32: [dir 0..1][batch 0..3][8192])
//            [256K):    block-done counter (u32)

__global__ __launch_bounds__(256) void chamfer_init_kernel(
    uint32_t* __restrict__ wsmin, uint32_t* __restrict__ counter)
{
    const int tid = blockIdx.x * 256 + threadIdx.x;   // 0..65535
    wsmin[tid] = 0xFFFFFFFFu;
    if (tid == 0) *counter = 0;
}

// one ring step: preds (QA,QZA->RA) and (QB,QZB->RB) vs targets t0..t3
#define STEP(QA, QZA, RA, QB, QZB, RB)                                  \
    do {                                                                \
        uint32_t d00 = sad_u16(tz0, QZA, sad_u16(t0, QA, 0u));          \
        uint32_t d01 = sad_u16(tz1, QZA, sad_u16(t1, QA, 0u));          \
        uint32_t d02 = sad_u16(tz2, QZA, sad_u16(t2, QA, 0u));          \
        uint32_t d03 = sad_u16(tz3, QZA, sad_u16(t3, QA, 0u));          \
        uint32_t d10 = sad_u16(tz0, QZB, sad_u16(t0, QB, 0u));          \
        uint32_t d11 = sad_u16(tz1, QZB, sad_u16(t1, QB, 0u));          \
        uint32_t d12 = sad_u16(tz2, QZB, sad_u16(t2, QB, 0u));          \
        uint32_t d13 = sad_u16(tz3, QZB, sad_u16(t3, QB, 0u));          \
        RA = min3_u32(d00, d01, min3_u32(d02, d03, RA));                \
        RB = min3_u32(d10, d11, min3_u32(d12, d13, RB));                \
        c0 = min3_u32(d00, d10, c0);                                    \
        c1 = min3_u32(d01, d11, c1);                                    \
        c2 = min3_u32(d02, d12, c2);                                    \
        c3 = min3_u32(d03, d13, c3);                                    \
    } while (0)

#define LOADQ(K, QXY, QZ)                                               \
    do {                                                                \
        const float* p_ = qsrc + (size_t)(pb + (K) * 16 + l16) * 3;     \
        QXY = quant(p_[0]) | (quant(p_[1]) << 16);                      \
        QZ  = quant(p_[2]);                                             \
    } while (0)

#define LOADT(M, TXY, TZ)                                               \
    do {                                                                \
        const float* p_ = tsrc + (size_t)(tb + g16 * 64 + (M) * 16 + l16) * 3; \
        TXY = quant(p_[0]) | (quant(p_[1]) << 16);                      \
        TZ  = quant(p_[2]);                                             \
    } while (0)

#define FWD(K, RA)                                                      \
    do {                                                                \
        uint32_t v_ = RA;                                               \
        v_ = umin32(v_, (uint32_t)__shfl_xor((int)v_, 16));             \
        v_ = umin32(v_, (uint32_t)__shfl_xor((int)v_, 32));             \
        if (g16 == 0) atomicMin(&fmin[pb + (K) * 16 + l16], v_);        \
    } while (0)

__global__ __launch_bounds__(256, 8) void chamfer_sym_kernel(
    const float* __restrict__ pred, const float* __restrict__ target,
    uint32_t* __restrict__ wsmin, uint32_t* __restrict__ counter,
    float* __restrict__ out)
{
    const int t    = threadIdx.x;
    const int wid  = t >> 6;
    const int lane = t & 63;
    const int g16  = lane >> 4;
    const int l16  = lane & 15;

    // global wave-tile id: [0, 8192)
    const int tid    = blockIdx.x * 4 + wid;
    const int b      = tid >> 11;          // batch 0..3
    const int rest   = tid & 2047;
    const int pblock = rest >> 5;          // 0..63  (128 preds each)
    const int tblock = rest & 31;          // 0..31  (256 targets each)

    const int pb = pblock * 128;
    const int tb = tblock * 256;
    const float* qsrc = pred   + (size_t)b * NPTS * 3;
    const float* tsrc = target + (size_t)b * NPTS * 3;

    // stationary preds (named scalars; quantized inline)
    uint32_t q0, q1, q2, q3, q4, q5, q6, q7;
    uint32_t qz0, qz1, qz2, qz3, qz4, qz5, qz6, qz7;
    LOADQ(0, q0, qz0);  LOADQ(1, q1, qz1);  LOADQ(2, q2, qz2);  LOADQ(3, q3, qz3);
    LOADQ(4, q4, qz4);  LOADQ(5, q5, qz5);  LOADQ(6, q6, qz6);  LOADQ(7, q7, qz7);
    uint32_t r0 = ~0u, r1 = ~0u, r2 = ~0u, r3 = ~0u,
             r4 = ~0u, r5 = ~0u, r6 = ~0u, r7 = ~0u;

    // rotating targets + col accs (named scalars)
    uint32_t t0, t1, t2, t3, tz0, tz1, tz2, tz3;
    LOADT(0, t0, tz0);  LOADT(1, t1, tz1);  LOADT(2, t2, tz2);  LOADT(3, t3, tz3);
    uint32_t c0 = ~0u, c1 = ~0u, c2 = ~0u, c3 = ~0u;

    // 16-round ring; after 16 rotations all rotating state is home.
    #pragma unroll 2
    for (int r = 0; r < 16; ++r) {
        STEP(q0, qz0, r0, q1, qz1, r1);
        STEP(q2, qz2, r2, q3, qz3, r3);
        STEP(q4, qz4, r4, q5, qz5, r5);
        STEP(q6, qz6, r6, q7, qz7, r7);
        t0 = rot16(t0);  t1 = rot16(t1);  t2 = rot16(t2);  t3 = rot16(t3);
        tz0 = rot16(tz0); tz1 = rot16(tz1); tz2 = rot16(tz2); tz3 = rot16(tz3);
        c0 = rot16(c0);  c1 = rot16(c1);  c2 = rot16(c2);  c3 = rot16(c3);
    }

    // forward: min across the 4 duplicate groups, atomic fold into wsmin
    uint32_t* fmin = wsmin + (size_t)b * NPTS;
    FWD(0, r0);  FWD(1, r1);  FWD(2, r2);  FWD(3, r3);
    FWD(4, r4);  FWD(5, r5);  FWD(6, r6);  FWD(7, r7);

    // backward: each group owns distinct targets
    uint32_t* bmin = wsmin + (size_t)(BATCH + b) * NPTS;
    atomicMin(&bmin[tb + g16 * 64 + 0  + l16], c0);
    atomicMin(&bmin[tb + g16 * 64 + 16 + l16], c1);
    atomicMin(&bmin[tb + g16 * 64 + 32 + l16], c2);
    atomicMin(&bmin[tb + g16 * 64 + 48 + l16], c3);

    // last-block-done reduction (deterministic full sum over wsmin)
    __shared__ float ssum[4];
    __shared__ uint32_t lastflag;
    __threadfence();   // release this block's atomicMins
    if (t == 0)
        lastflag = (atomicAdd(counter, 1u) == NBLK - 1);
    __syncthreads();
    if (!lastflag) return;
    __threadfence();   // acquire all blocks' mins

    const uint4* p = reinterpret_cast<const uint4*>(wsmin);   // 16384 uint4
    float s = 0.0f;
    #pragma unroll 4
    for (int i = 0; i < 64; ++i) {
        uint4 v = p[t + i * 256];
        s += (float)v.x + (float)v.y + (float)v.z + (float)v.w;
    }
    #pragma unroll
    for (int off = 32; off > 0; off >>= 1)
        s += __shfl_down(s, off);
    if (lane == 0) ssum[wid] = s;
    __syncthreads();
    if (t == 0)
        out[0] = (ssum[0] + ssum[1] + ssum[2] + ssum[3])
               * (1.0f / (QSCALE * (float)BATCH));
}

extern "C" void kernel_launch(void* const* d_in, const int* in_sizes, int n_in,
                              void* d_out, int out_size, void* d_ws, size_t ws_size,
                              hipStream_t stream) {
    const float* pred   = (const float*)d_in[0];
    const float* target = (const float*)d_in[1];
    float* out = (float*)d_out;
    uint32_t* wsmin   = (uint32_t*)d_ws;                       // 256 KiB
    uint32_t* counter = (uint32_t*)((char*)d_ws + 256 * 1024);

    chamfer_init_kernel<<<256, 256, 0, stream>>>(wsmin, counter);
    chamfer_sym_kernel<<<NBLK, 256, 0, stream>>>(pred, target, wsmin, counter, out);
}

// Round 16
// 144.350 us; speedup vs baseline: 1.0260x; 1.0260x over previous
//
#include <hip/hip_runtime.h>
#include <stdint.h>

// Chamfer L1, B=4, N=M=8192, 3-D points — SYMMETRIC single-pass.
// R16 = R10 (verified 37.8 us) + ONLY the fused last-block reduce tail.
// Single-variable isolation: R11/R13/R15 (all ~145 us, VGPR=28 scratch
// spill) bundled {inline-quant(A), fused-tail(B)}; this tests B alone.
// Everything in the sym ring / input path is byte-identical to R10:
// prep quantizes all points once into wsq (u16 fixed point, 4096/unit,
// +8 offset); wave tile = 128 preds x 256 targets; 4 groups of 16 lanes;
// lane owns NP=8 preds (stationary, row accs) + NT=4 targets (rotating
// cols via in-place DPP row_ror:1, zero LDS); pair = 2x v_sad_u16 +
// v_min3_u32 (asm). 8192 waves = 2048 blocks, 8 waves/SIMD.

#define BATCH    4
#define NPTS     8192
#define QSCALE   4096.0f
#define QOFFS    8.0f
#define NP       8
#define NT       4
#define NPTS_TOT (2 * BATCH * NPTS)   // 65536
#define NBLK     2048

static __device__ __forceinline__ uint32_t sad_u16(uint32_t a, uint32_t b, uint32_t c) {
#if __has_builtin(__builtin_amdgcn_sad_u16)
    return __builtin_amdgcn_sad_u16(a, b, c);
#else
    uint32_t d;
    asm("v_sad_u16 %0, %1, %2, %3" : "=v"(d) : "v"(a), "v"(b), "v"(c));
    return d;
#endif
}

static __device__ __forceinline__ uint32_t min3_u32(uint32_t a, uint32_t b, uint32_t c) {
    uint32_t d;
    asm("v_min3_u32 %0, %1, %2, %3" : "=v"(d) : "v"(a), "v"(b), "v"(c));
    return d;
}

static __device__ __forceinline__ uint32_t umin32(uint32_t a, uint32_t b) {
    return a < b ? a : b;
}

// in-place rotate within each 16-lane row: lane l receives lane (l+1)&15
static __device__ __forceinline__ uint32_t rot16(uint32_t v) {
    return (uint32_t)__builtin_amdgcn_update_dpp((int)v, (int)v, 0x121, 0xF, 0xF, false);
}

static __device__ __forceinline__ uint32_t quant(float x) {
    float v = (x + QOFFS) * QSCALE;
    v = fminf(fmaxf(v, 0.0f), 65535.0f);
    return (uint32_t)(v + 0.5f);
}

// ws layout: [0, 256K):    wsmin (64K u32: [dir 0..1][batch 0..3][8192])
//            [256K, 768K): wsq (65536 uint2 quantized points)
//            [768K):       block-done counter (u32)

__global__ __launch_bounds__(256) void chamfer_prep_kernel(
    const float* __restrict__ pred, const float* __restrict__ target,
    uint32_t* __restrict__ wsmin, uint2* __restrict__ wsq,
    uint32_t* __restrict__ counter)
{
    const int tid = blockIdx.x * 256 + threadIdx.x;   // 0..65535
    if (tid == 0) *counter = 0;
    wsmin[tid] = 0xFFFFFFFFu;
    const float* src = (tid < NPTS_TOT / 2)
                     ? pred + (size_t)tid * 3
                     : target + (size_t)(tid - NPTS_TOT / 2) * 3;
    wsq[tid] = make_uint2(quant(src[0]) | (quant(src[1]) << 16), quant(src[2]));
}

__global__ __launch_bounds__(256, 8) void chamfer_sym_kernel(
    const uint2* __restrict__ wsq, uint32_t* __restrict__ wsmin,
    uint32_t* __restrict__ counter, float* __restrict__ out)
{
    const int t    = threadIdx.x;
    const int wid  = t >> 6;
    const int lane = t & 63;
    const int g16  = lane >> 4;
    const int l16  = lane & 15;

    // global wave-tile id: [0, 8192)
    const int tid    = blockIdx.x * 4 + wid;
    const int b      = tid >> 11;          // batch 0..3
    const int rest   = tid & 2047;
    const int pblock = rest >> 5;          // 0..63  (128 preds each)
    const int tblock = rest & 31;          // 0..31  (256 targets each)

    const int pb = pblock * 128;
    const int tb = tblock * 256;
    const uint2* qsrc = wsq + (size_t)b * NPTS;                  // preds of batch b
    const uint2* tsrc = wsq + (size_t)(BATCH + b) * NPTS;        // targets of batch b

    // stationary preds + row accs
    uint32_t qxy[NP], qz[NP], rowacc[NP];
    #pragma unroll
    for (int k = 0; k < NP; ++k) {
        uint2 v = qsrc[pb + k * 16 + l16];
        qxy[k] = v.x;  qz[k] = v.y;  rowacc[k] = 0xFFFFFFFFu;
    }

    // rotating targets + col accs (group owns 64 distinct targets)
    uint32_t txy[NT], tz[NT], colacc[NT];
    #pragma unroll
    for (int m = 0; m < NT; ++m) {
        uint2 v = tsrc[tb + g16 * 64 + m * 16 + l16];
        txy[m] = v.x;  tz[m] = v.y;  colacc[m] = 0xFFFFFFFFu;
    }

    // 16-round ring: NP x NT pairs per round, both accs updated, then
    // targets+colaccs rotate one lane; after 16 rounds data is home.
    #pragma unroll 4
    for (int r = 0; r < 16; ++r) {
        #pragma unroll
        for (int kk = 0; kk < NP; kk += 2) {
            uint32_t d0[NT], d1[NT];
            #pragma unroll
            for (int m = 0; m < NT; ++m) {
                d0[m] = sad_u16(tz[m], qz[kk],     sad_u16(txy[m], qxy[kk],     0u));
                d1[m] = sad_u16(tz[m], qz[kk + 1], sad_u16(txy[m], qxy[kk + 1], 0u));
            }
            rowacc[kk]     = min3_u32(d0[0], d0[1], min3_u32(d0[2], d0[3], rowacc[kk]));
            rowacc[kk + 1] = min3_u32(d1[0], d1[1], min3_u32(d1[2], d1[3], rowacc[kk + 1]));
            #pragma unroll
            for (int m = 0; m < NT; ++m)
                colacc[m] = min3_u32(d0[m], d1[m], colacc[m]);
        }
        #pragma unroll
        for (int m = 0; m < NT; ++m) {
            txy[m]    = rot16(txy[m]);
            tz[m]     = rot16(tz[m]);
            colacc[m] = rot16(colacc[m]);
        }
    }

    // forward (pred as query): min across the 4 duplicate groups, then atomics
    uint32_t* fmin = wsmin + (size_t)b * NPTS;
    #pragma unroll
    for (int k = 0; k < NP; ++k) {
        uint32_t v = rowacc[k];
        v = umin32(v, (uint32_t)__shfl_xor((int)v, 16));
        v = umin32(v, (uint32_t)__shfl_xor((int)v, 32));
        if (g16 == 0)
            atomicMin(&fmin[pb + k * 16 + l16], v);
    }

    // backward (target as query): groups own distinct targets
    uint32_t* bmin = wsmin + (size_t)(BATCH + b) * NPTS;
    #pragma unroll
    for (int m = 0; m < NT; ++m)
        atomicMin(&bmin[tb + g16 * 64 + m * 16 + l16], colacc[m]);

    // --- fused last-block-done reduction (the ONLY change vs R10) ---
    __shared__ float ssum[4];
    __shared__ uint32_t lastflag;
    __threadfence();   // release this block's atomicMins
    if (t == 0)
        lastflag = (atomicAdd(counter, 1u) == NBLK - 1);
    __syncthreads();
    if (!lastflag) return;
    __threadfence();   // acquire all blocks' mins

    const uint4* p = reinterpret_cast<const uint4*>(wsmin);   // 16384 uint4
    float s = 0.0f;
    #pragma unroll 4
    for (int i = 0; i < 64; ++i) {
        uint4 v = p[t + i * 256];
        s += (float)v.x + (float)v.y + (float)v.z + (float)v.w;
    }
    #pragma unroll
    for (int off = 32; off > 0; off >>= 1)
        s += __shfl_down(s, off);
    if (lane == 0) ssum[wid] = s;
    __syncthreads();
    if (t == 0)
        out[0] = (ssum[0] + ssum[1] + ssum[2] + ssum[3])
               * (1.0f / (QSCALE * (float)BATCH));
}

extern "C" void kernel_launch(void* const* d_in, const int* in_sizes, int n_in,
                              void* d_out, int out_size, void* d_ws, size_t ws_size,
                              hipStream_t stream) {
    const float* pred   = (const float*)d_in[0];
    const float* target = (const float*)d_in[1];
    float* out = (float*)d_out;
    uint32_t* wsmin   = (uint32_t*)d_ws;                         // 256 KiB
    uint2*    wsq     = (uint2*)((char*)d_ws + 256 * 1024);      // 512 KiB
    uint32_t* counter = (uint32_t*)((char*)d_ws + 768 * 1024);

    chamfer_prep_kernel<<<NPTS_TOT / 256, 256, 0, stream>>>(pred, target, wsmin, wsq, counter);

    // 8192 wave-tiles, 4 waves/block -> 2048 blocks (8/CU, 8 waves/SIMD)
    chamfer_sym_kernel<<<NBLK, 256, 0, stream>>>(wsq, wsmin, counter, out);
}

// Round 17
// 37.411 us; speedup vs baseline: 3.9589x; 3.8585x over previous
//
#include <hip/hip_runtime.h>
#include <stdint.h>

// Chamfer L1, B=4, N=M=8192, 3-D points — SYMMETRIC single-pass.
// R17 = R10 (verified 37.8 us) + atomic-tail reduction (2x fewer global
// atomics), NO fusion (R11/R13/R15/R16 all spilled; fused tail is toxic).
// Theory: all blocks finish the ~18 us ring in lockstep then dump 3.1M
// device-scope atomicMins -> ~13 us serialized tail. Cut it:
//  - block's 4 waves share one TBLOCK (same 256 targets, 4 pblocks):
//    bwd colaccs combined in LDS (DS atomicMin), 256 global atomics/block
//    instead of 1024 (2.1M -> 524K).
//  - fwd atomics spread across the 4 lane-groups (g16 == k>>1).
// Ring is byte-identical to R10: u16 quant (4096/unit, +8), pair =
// 2x v_sad_u16 + v_min3_u32, NP=8 preds stationary, NT=4 targets rotating
// via in-place DPP row_ror:1, zero LDS in the loop. 2048 blocks, 8 w/SIMD.

#define BATCH    4
#define NPTS     8192
#define QSCALE   4096.0f
#define QOFFS    8.0f
#define NP       8
#define NT       4
#define NPTS_TOT (2 * BATCH * NPTS)   // 65536

static __device__ __forceinline__ uint32_t sad_u16(uint32_t a, uint32_t b, uint32_t c) {
#if __has_builtin(__builtin_amdgcn_sad_u16)
    return __builtin_amdgcn_sad_u16(a, b, c);
#else
    uint32_t d;
    asm("v_sad_u16 %0, %1, %2, %3" : "=v"(d) : "v"(a), "v"(b), "v"(c));
    return d;
#endif
}

static __device__ __forceinline__ uint32_t min3_u32(uint32_t a, uint32_t b, uint32_t c) {
    uint32_t d;
    asm("v_min3_u32 %0, %1, %2, %3" : "=v"(d) : "v"(a), "v"(b), "v"(c));
    return d;
}

static __device__ __forceinline__ uint32_t umin32(uint32_t a, uint32_t b) {
    return a < b ? a : b;
}

// in-place rotate within each 16-lane row: lane l receives lane (l+1)&15
static __device__ __forceinline__ uint32_t rot16(uint32_t v) {
    return (uint32_t)__builtin_amdgcn_update_dpp((int)v, (int)v, 0x121, 0xF, 0xF, false);
}

static __device__ __forceinline__ uint32_t quant(float x) {
    float v = (x + QOFFS) * QSCALE;
    v = fminf(fmaxf(v, 0.0f), 65535.0f);
    return (uint32_t)(v + 0.5f);
}

// ws layout: [0, 256K):    wsmin (64K u32: [dir 0..1][batch 0..3][8192])
//            [256K, 768K): wsq (65536 uint2 quantized points)

__global__ __launch_bounds__(256) void chamfer_prep_kernel(
    const float* __restrict__ pred, const float* __restrict__ target,
    uint32_t* __restrict__ wsmin, uint2* __restrict__ wsq,
    float* __restrict__ out)
{
    const int tid = blockIdx.x * 256 + threadIdx.x;   // 0..65535
    if (tid == 0) out[0] = 0.0f;
    wsmin[tid] = 0xFFFFFFFFu;
    const float* src = (tid < NPTS_TOT / 2)
                     ? pred + (size_t)tid * 3
                     : target + (size_t)(tid - NPTS_TOT / 2) * 3;
    wsq[tid] = make_uint2(quant(src[0]) | (quant(src[1]) << 16), quant(src[2]));
}

__global__ __launch_bounds__(256, 8) void chamfer_sym_kernel(
    const uint2* __restrict__ wsq, uint32_t* __restrict__ wsmin)
{
    __shared__ uint32_t bacc[256];   // block-combined bwd mins (1 KiB)

    const int t    = threadIdx.x;
    const int wid  = t >> 6;
    const int lane = t & 63;
    const int g16  = lane >> 4;
    const int l16  = lane & 15;

    // global wave-tile id: [0, 8192). Block's 4 waves: SAME tblock,
    // 4 consecutive pblocks (enables LDS combine of bwd mins).
    const int tid    = blockIdx.x * 4 + wid;
    const int b      = tid >> 11;          // batch 0..3
    const int rest   = tid & 2047;
    const int tblock = rest >> 6;          // 0..31  (256 targets each)
    const int pblock = rest & 63;          // 0..63  (128 preds each)

    const int pb = pblock * 128;
    const int tb = tblock * 256;
    const uint2* qsrc = wsq + (size_t)b * NPTS;                  // preds of batch b
    const uint2* tsrc = wsq + (size_t)(BATCH + b) * NPTS;        // targets of batch b

    bacc[t] = 0xFFFFFFFFu;   // init LDS combine buffer (no barrier needed yet)

    // stationary preds + row accs
    uint32_t qxy[NP], qz[NP], rowacc[NP];
    #pragma unroll
    for (int k = 0; k < NP; ++k) {
        uint2 v = qsrc[pb + k * 16 + l16];
        qxy[k] = v.x;  qz[k] = v.y;  rowacc[k] = 0xFFFFFFFFu;
    }

    // rotating targets + col accs (group owns 64 distinct targets)
    uint32_t txy[NT], tz[NT], colacc[NT];
    #pragma unroll
    for (int m = 0; m < NT; ++m) {
        uint2 v = tsrc[tb + g16 * 64 + m * 16 + l16];
        txy[m] = v.x;  tz[m] = v.y;  colacc[m] = 0xFFFFFFFFu;
    }

    // 16-round ring: NP x NT pairs per round, both accs updated, then
    // targets+colaccs rotate one lane; after 16 rounds data is home.
    #pragma unroll 4
    for (int r = 0; r < 16; ++r) {
        #pragma unroll
        for (int kk = 0; kk < NP; kk += 2) {
            uint32_t d0[NT], d1[NT];
            #pragma unroll
            for (int m = 0; m < NT; ++m) {
                d0[m] = sad_u16(tz[m], qz[kk],     sad_u16(txy[m], qxy[kk],     0u));
                d1[m] = sad_u16(tz[m], qz[kk + 1], sad_u16(txy[m], qxy[kk + 1], 0u));
            }
            rowacc[kk]     = min3_u32(d0[0], d0[1], min3_u32(d0[2], d0[3], rowacc[kk]));
            rowacc[kk + 1] = min3_u32(d1[0], d1[1], min3_u32(d1[2], d1[3], rowacc[kk + 1]));
            #pragma unroll
            for (int m = 0; m < NT; ++m)
                colacc[m] = min3_u32(d0[m], d1[m], colacc[m]);
        }
        #pragma unroll
        for (int m = 0; m < NT; ++m) {
            txy[m]    = rot16(txy[m]);
            tz[m]     = rot16(tz[m]);
            colacc[m] = rot16(colacc[m]);
        }
    }

    // forward (pred as query): min across the 4 duplicate groups; group
    // (k>>1) issues the atomic for pred row k (all groups hold the min).
    uint32_t* fmin = wsmin + (size_t)b * NPTS;
    #pragma unroll
    for (int k = 0; k < NP; ++k) {
        uint32_t v = rowacc[k];
        v = umin32(v, (uint32_t)__shfl_xor((int)v, 16));
        v = umin32(v, (uint32_t)__shfl_xor((int)v, 32));
        if (g16 == (k >> 1))
            atomicMin(&fmin[pb + k * 16 + l16], v);
    }

    // backward (target as query): combine the block's 4 waves in LDS,
    // then one coalesced global atomic per target (256 per block).
    #pragma unroll
    for (int m = 0; m < NT; ++m)
        atomicMin(&bacc[g16 * 64 + m * 16 + l16], colacc[m]);
    __syncthreads();

    uint32_t* bmin = wsmin + (size_t)(BATCH + b) * NPTS;
    atomicMin(&bmin[tb + t], bacc[t]);
}

__global__ __launch_bounds__(256) void chamfer_reduce_kernel(
    const uint32_t* __restrict__ wsmin, float* __restrict__ out)
{
    const int t = threadIdx.x;
    const uint4* p = reinterpret_cast<const uint4*>(wsmin);   // 16384 uint4
    float s = 0.0f;
    #pragma unroll
    for (int i = 0; i < 4; ++i) {
        uint4 v = p[blockIdx.x * 1024 + i * 256 + t];
        s += (float)v.x + (float)v.y + (float)v.z + (float)v.w;
    }
    #pragma unroll
    for (int off = 32; off > 0; off >>= 1)
        s += __shfl_down(s, off);
    if ((t & 63) == 0)
        atomicAdd(out, s * (1.0f / (QSCALE * (float)BATCH)));
}

extern "C" void kernel_launch(void* const* d_in, const int* in_sizes, int n_in,
                              void* d_out, int out_size, void* d_ws, size_t ws_size,
                              hipStream_t stream) {
    const float* pred   = (const float*)d_in[0];
    const float* target = (const float*)d_in[1];
    float* out = (float*)d_out;
    uint32_t* wsmin = (uint32_t*)d_ws;                       // 256 KiB
    uint2*    wsq   = (uint2*)((char*)d_ws + 256 * 1024);    // 512 KiB

    chamfer_prep_kernel<<<NPTS_TOT / 256, 256, 0, stream>>>(pred, target, wsmin, wsq, out);

    // 8192 wave-tiles, 4 waves/block -> 2048 blocks (8/CU, 8 waves/SIMD)
    chamfer_sym_kernel<<<2048, 256, 0, stream>>>(wsq, wsmin);

    chamfer_reduce_kernel<<<16, 256, 0, stream>>>(wsmin, out);
}